// Round 3
// baseline (599.773 us; speedup 1.0000x reference)
//
#include <hip/hip_runtime.h>

typedef __bf16 bf16x8 __attribute__((ext_vector_type(8)));
typedef float  f32x4  __attribute__((ext_vector_type(4)));
typedef unsigned short us8 __attribute__((ext_vector_type(8)));

__device__ __forceinline__ unsigned short f2bf(float f) {
    union { float f; unsigned u; } c; c.f = f;
    unsigned u = c.u;
    u += 0x7FFFu + ((u >> 16) & 1u);   // RNE; inputs finite
    return (unsigned short)(u >> 16);
}

// async 16B global -> LDS (dest = wave-uniform base + lane*16)
__device__ __forceinline__ void gl2lds16(const void* g, void* l) {
    __builtin_amdgcn_global_load_lds(
        (const __attribute__((address_space(1))) unsigned int*)g,
        (__attribute__((address_space(3))) unsigned int*)l, 16, 0, 0);
}

#define NXP   340           // 10*34 halo pixels
#define WTAP  (128 * 64)    // ushorts per tap in wpad (16 KB, swizzle baked in)

// -------- weight pre-transform: OIHW f32 -> [tap][co][slot] bf16 ------------
// Slot s of row co holds ci-granule g = s ^ (co&7)  (8 bf16 per granule).
// Baking the XOR swizzle into the GLOBAL layout keeps the conv kernel's
// global_load_lds staging linear-dest (wave-uniform rule) while giving
// bank-conflict-free, 16B-aligned ds_read_b128 B-frag reads.
__global__ void __launch_bounds__(256) wxform(const float* __restrict__ W,
                                              unsigned short* __restrict__ wpad) {
    int o = blockIdx.x * 256 + threadIdx.x;        // 9*128*64 = 73728
    if (o < 9 * WTAP) {
        int tap = o / WTAP;
        int r   = o % WTAP;
        int co  = r >> 6;
        int q   = r & 63;
        int s   = q >> 3;                  // slot
        int e   = q & 7;
        int g   = s ^ (co & 7);            // granule stored at this slot
        int ci  = g * 8 + e;
        wpad[o] = f2bf(W[co * 576 + ci * 9 + tap]);   // W[co][ci][kh][kw]
    }
}

struct SmemT {
    unsigned short x[NXP * 64];      // 43520 B : halo [px][slot], slot = g ^ ((px>>1)&7)
    unsigned short w[2][WTAP];       // 32768 B : double-buffered tap weights (swizzled)
};                                   // total 76288 B -> 2 blocks/CU

// -------- fused conv3x3 + bias + avgpool2 + sigmoid + per-image sum --------
// Block: 8 rows x 32 cols x 128 co. Wave v owns rows {2v, 2v+1} (one pool row).
__global__ void __launch_bounds__(256, 2)
conv_fused(const float* __restrict__ x,
           const unsigned short* __restrict__ wpad,
           const float* __restrict__ bias,
           float* __restrict__ out)
{
    __shared__ __align__(16) SmemT sm;
    __shared__ float red[4];

    const int tid  = threadIdx.x;
    const int wave = tid >> 6;
    const int lane = tid & 63;
    const int lq   = lane >> 4;
    const int lm   = lane & 15;

    const int ct = blockIdx.x;        // 0..3   col tile (32 wide)
    const int rt = blockIdx.y;        // 0..15  row tile (8 tall)
    const int n  = blockIdx.z;        // 0..63  image

    const int h0 = rt * 8;
    const int w0 = ct * 32;
    const float* xn = x + (size_t)n * (64u * 128u * 128u);

    // ---- async prefetch of tap-0 weights (16 x 1KB chunks, 4 per wave)
    for (int c = wave; c < 16; c += 4)
        gl2lds16(wpad + c * 512 + lane * 8, &sm.w[0][c * 512]);

    // ---- stage x halo: 64ci x 10h x 34w -> LDS [px][slot] bf16 (swizzled).
    // Task = 8 ci (one granule) x 2 consecutive w pixels. float2 loads along w
    // (coalesced: 17 consecutive lanes cover one 136B row segment), packed RNE
    // cvt to bf16, two 16B ds_write_b128 — both pixels of a pair share the
    // swizzle key (px>>1)&7, so each store's 16 lanes sweep all 8 bank slots.
    for (int it = 0; it < 6; ++it) {
        int t = it * 256 + tid;
        if (t < 1360) {                    // 8 cig * (10 rows * 17 wpairs)
            int g  = t / 170;              // ci-group (8 ci)
            int pp = t % 170;
            int hh = pp / 17, wq = pp % 17;
            int h = h0 + hh, w = w0 + wq * 2;
            bool ok = (h < 128) && (w < 128);   // w even, never straddles row end
            const float* src = xn + (size_t)(g * 8) * 16384 + h * 128 + w;
            float lo[8], hi[8];
            #pragma unroll
            for (int j = 0; j < 8; ++j) {
                float2 v = ok ? *(const float2*)(src + j * 16384) : float2{0.f, 0.f};
                lo[j] = v.x; hi[j] = v.y;
            }
            union { us8 u; bf16x8 b; } va, vb;
            #pragma unroll
            for (int j = 0; j < 8; ++j) {
                va.b[j] = (__bf16)lo[j];   // v_cvt_pk_bf16_f32, RNE
                vb.b[j] = (__bf16)hi[j];
            }
            int px   = hh * 34 + wq * 2;
            int key  = (hh * 17 + wq) & 7;         // == (px>>1)&7, same for px+1
            char* base = (char*)sm.x + px * 128 + ((g ^ key) << 4);
            *(us8*)(base      ) = va.u;
            *(us8*)(base + 128) = vb.u;
        }
    }

    // bias preload (co = nt*16 + lm)
    float bv[8];
    #pragma unroll
    for (int nt = 0; nt < 8; ++nt) bv[nt] = bias[nt * 16 + lm];

    // lane-constant B-frag slot offsets (bytes) for kc=0/1
    const int wb0 = lm * 128 + (((0 << 2) | lq) ^ (lm & 7)) * 16;
    const int wb1 = lm * 128 + (((1 << 2) | lq) ^ (lm & 7)) * 16;

    f32x4 acc[4][8];                  // [rl*2+ch][nt] : 128 VGPRs
    #pragma unroll
    for (int mt = 0; mt < 4; ++mt)
        #pragma unroll
        for (int nt = 0; nt < 8; ++nt)
            acc[mt][nt] = (f32x4){0.f, 0.f, 0.f, 0.f};

    __syncthreads();   // drains x ds_writes + tap0 global_load_lds

    // ---- K loop: 9 taps, weights double-buffered, ONE barrier per tap ----
    for (int tap = 0; tap < 9; ++tap) {
        const int cur = tap & 1;
        if (tap < 8) {                // prefetch tap+1 into other buffer
            const unsigned short* wt = wpad + (tap + 1) * WTAP;
            for (int c = wave; c < 16; c += 4)
                gl2lds16(wt + c * 512 + lane * 8, &sm.w[cur ^ 1][c * 512]);
        }
        const int kh = tap / 3, kw = tap - kh * 3;

        // A frags: A[m=lm][k=lq*8+j], m = pixel col; swizzled slot read
        bf16x8 a[2][2][2];            // [rl][ch][kc]
        #pragma unroll
        for (int rl = 0; rl < 2; ++rl)
            #pragma unroll
            for (int ch = 0; ch < 2; ++ch)
                #pragma unroll
                for (int kc = 0; kc < 2; ++kc) {
                    int px   = (2 * wave + rl + kh) * 34 + ch * 16 + lm + kw;
                    int slot = ((kc << 2) | lq) ^ ((px >> 1) & 7);
                    a[rl][ch][kc] = *(const bf16x8*)((const char*)sm.x + px * 128 + (slot << 4));
                }
        __builtin_amdgcn_s_setprio(1);   // favor MFMA wave vs co-resident block's staging
        const char* wbase = (const char*)sm.w[cur];
        #pragma unroll
        for (int nt = 0; nt < 8; ++nt) {
            #pragma unroll
            for (int kc = 0; kc < 2; ++kc) {
                bf16x8 b = *(const bf16x8*)(wbase + nt * 2048 + (kc ? wb1 : wb0));
                #pragma unroll
                for (int rl = 0; rl < 2; ++rl)
                    #pragma unroll
                    for (int ch = 0; ch < 2; ++ch)
                        acc[rl * 2 + ch][nt] = __builtin_amdgcn_mfma_f32_16x16x32_bf16(
                            a[rl][ch][kc], b, acc[rl * 2 + ch][nt], 0, 0, 0);
            }
        }
        __builtin_amdgcn_s_setprio(0);
        __syncthreads();  // all waves done with w[cur]; drains prefetch into w[cur^1]
    }

    // ---- in-register epilogue: D rows rl=0/1 are a vertical pool pair; the 4
    // regs rr=0..3 (pixel cols lq*4+rr) give two horizontal pool pairs. ----
    float part = 0.0f;
    const int ph = rt * 4 + wave;                 // pool row (wave-uniform)
    if (ph < 63) {
        #pragma unroll
        for (int ch = 0; ch < 2; ++ch) {
            const int pwb = ct * 16 + ch * 8 + lq * 2;
            #pragma unroll
            for (int nt = 0; nt < 8; ++nt) {
                f32x4 s = acc[ch][nt] + acc[2 + ch][nt];   // vertical pool sum
                float p0 = s[0] + s[1];                    // cols (0,1) of quad
                float p1 = s[2] + s[3];                    // cols (2,3)
                float bb = bv[nt];
                if (pwb < 63) {
                    float v = 0.25f * p0 + bb;
                    part += 1.0f / (1.0f + __expf(-v));
                }
                if (pwb + 1 < 63) {
                    float v = 0.25f * p1 + bb;
                    part += 1.0f / (1.0f + __expf(-v));
                }
            }
        }
    }

    // ---- block reduce -> one atomicAdd per block ----
    #pragma unroll
    for (int off = 32; off > 0; off >>= 1)
        part += __shfl_down(part, off, 64);
    if (lane == 0) red[wave] = part;
    __syncthreads();
    if (tid == 0) atomicAdd(&out[n], red[0] + red[1] + red[2] + red[3]);
}

extern "C" void kernel_launch(void* const* d_in, const int* in_sizes, int n_in,
                              void* d_out, int out_size, void* d_ws, size_t ws_size,
                              hipStream_t stream) {
    const float* x = (const float*)d_in[0];
    const float* W = (const float*)d_in[1];
    const float* b = (const float*)d_in[2];
    float* out = (float*)d_out;
    unsigned short* wpad = (unsigned short*)d_ws;   // 147,456 B used

    hipMemsetAsync(d_out, 0, 64 * sizeof(float), stream);
    wxform<<<(9 * WTAP + 255) / 256, 256, 0, stream>>>(W, wpad);
    conv_fused<<<dim3(4, 16, 64), 256, 0, stream>>>(x, wpad, b, out);
}